// Round 9
// baseline (1252.519 us; speedup 1.0000x reference)
//
#include <hip/hip_runtime.h>

#define NN 100000
#define NE 1600000
#define NT (NE + NN)     // edges incl. self-loops
#define FD 128
#define NC 10
#define NG 64

#define NBKT ((NN + 127) >> 7)   // 782 buckets of 128 nodes
#define CAP 3072                 // LDS edge cap per bucket (mean 2046, sigma ~45)

typedef __attribute__((ext_vector_type(8))) short short8v;   // 8 bf16 (4 VGPRs)
typedef __attribute__((ext_vector_type(4))) float f32x4;

__device__ inline ushort f2bf(float x) {                     // round-to-nearest-even
  unsigned u = __float_as_uint(x);
  return (ushort)((u + 0x7FFF + ((u >> 16) & 1)) >> 16);
}
__device__ inline float bf2f(ushort h) { return __uint_as_float(((unsigned)h) << 16); }

// ---------- binned CSR build ----------

__global__ void k_zero_int(int* __restrict__ a, int n) {
  int i = blockIdx.x * 256 + threadIdx.x;
  if (i < n) a[i] = 0;
}

__global__ void k_bcount(const int* __restrict__ dst, int* __restrict__ bcnt) {
  int e = blockIdx.x * 256 + threadIdx.x;
  if (e < NE) atomicAdd(&bcnt[dst[e] >> 7], 1);
}

// single block, 1024 threads: exclusive scan of bucket counts; zero cursors
__global__ void k_bscan(const int* __restrict__ bcnt, int* __restrict__ boff,
                        int* __restrict__ bcur) {
  __shared__ int sh[1024];
  int t = threadIdx.x;
  int v = (t < NBKT) ? bcnt[t] : 0;
  sh[t] = v;
  __syncthreads();
  for (int off = 1; off < 1024; off <<= 1) {
    int u = (t >= off) ? sh[t - off] : 0;
    __syncthreads();
    sh[t] += u;
    __syncthreads();
  }
  if (t < NBKT) {
    boff[t] = sh[t] - v;          // exclusive
    bcur[t] = 0;
  }
  if (t == NBKT - 1) boff[NBKT] = sh[t];   // = NE
}

// append packed (local_dst<<17 | src) into the bucket's contiguous region
__global__ void k_bfill(const int* __restrict__ src, const int* __restrict__ dst,
                        const int* __restrict__ boff, int* __restrict__ bcur,
                        unsigned* __restrict__ binned) {
  int e = blockIdx.x * 256 + threadIdx.x;
  if (e >= NE) return;
  int d = dst[e], s = src[e];
  int b = d >> 7;
  int slot = boff[b] + atomicAdd(&bcur[b], 1);
  binned[slot] = ((unsigned)(d & 127) << 17) | (unsigned)s;
}

// one block per bucket: local degree count, local scan (+self), emit rowptr/dinv,
// LDS scatter, contiguous coalesced CSR write. Fallback to global scatter if >CAP.
__global__ __launch_bounds__(256) void k_csr_bucket(
    const int* __restrict__ boff, const unsigned* __restrict__ binned,
    int* __restrict__ rowptr, float* __restrict__ dinv, int* __restrict__ csr_src) {
  __shared__ unsigned varr[CAP];
  __shared__ int earr[CAP + 128];
  __shared__ int deg[128];
  __shared__ int sh[128];
  int b = blockIdx.x, tid = threadIdx.x;
  int e0 = boff[b], e1 = boff[b + 1], seg = e1 - e0;
  int n0 = b << 7;
  int nb = NN - n0; if (nb > 128) nb = 128;
  int gbase = e0 + n0;                      // + one self per preceding node
  if (tid < 128) deg[tid] = 0;
  __syncthreads();
  bool fast = (seg <= CAP);
  if (fast) {
    for (int i = tid; i < seg; i += 256) {
      unsigned v = binned[e0 + i];
      varr[i] = v;
      atomicAdd(&deg[(v >> 17) & 127], 1);
    }
  } else {
    for (int i = tid; i < seg; i += 256) {
      unsigned v = binned[e0 + i];
      atomicAdd(&deg[(v >> 17) & 127], 1);
    }
  }
  __syncthreads();
  int dl = 0;
  if (tid < 128) {
    dl = (tid < nb) ? deg[tid] + 1 : 0;     // +1 self-loop
    sh[tid] = dl;
  }
  __syncthreads();
  for (int off = 1; off < 128; off <<= 1) {
    int u = 0;
    if (tid < 128 && tid >= off) u = sh[tid - off];
    __syncthreads();
    if (tid < 128) sh[tid] += u;
    __syncthreads();
  }
  int excl = 0;
  if (tid < nb) {
    excl = sh[tid] - dl;
    rowptr[n0 + tid] = gbase + excl;
    dinv[n0 + tid] = rsqrtf((float)dl);
    if (fast) earr[excl] = n0 + tid;        // self-loop in first slot
    else      csr_src[gbase + excl] = n0 + tid;
  }
  __syncthreads();
  if (tid < 128) deg[tid] = (tid < nb) ? (excl + 1) : 0;   // cursor after self
  __syncthreads();
  if (fast) {
    for (int i = tid; i < seg; i += 256) {
      unsigned v = varr[i];
      int l = (v >> 17) & 127;
      int pos = atomicAdd(&deg[l], 1);
      earr[pos] = (int)(v & 0x1FFFF);
    }
    __syncthreads();
    int tot = seg + nb;
    for (int i = tid; i < tot; i += 256) csr_src[gbase + i] = earr[i];
  } else {
    for (int i = tid; i < seg; i += 256) {
      unsigned v = binned[e0 + i];
      int l = (v >> 17) & 127;
      int pos = atomicAdd(&deg[l], 1);
      csr_src[gbase + pos] = (int)(v & 0x1FFFF);
    }
  }
  if (b == 0 && tid == 0) rowptr[NN] = NT;
}

// ---------- split-bf16 prep ----------

__global__ void k_split(const float* __restrict__ X, ushort* __restrict__ Hh,
                        ushort* __restrict__ Hl) {
  int t = blockIdx.x * 256 + threadIdx.x;
  if (t >= NN * FD / 4) return;
  float4 v = ((const float4*)X)[t];
  ushort4 h, l;
  h.x = f2bf(v.x); l.x = f2bf(v.x - bf2f(h.x));
  h.y = f2bf(v.y); l.y = f2bf(v.y - bf2f(h.y));
  h.z = f2bf(v.z); l.z = f2bf(v.z - bf2f(h.z));
  h.w = f2bf(v.w); l.w = f2bf(v.w - bf2f(h.w));
  ((ushort4*)Hh)[t] = h;
  ((ushort4*)Hl)[t] = l;
}

// Pack W[k][col] into MFMA B-fragment order, split hi/lo:
// packed[(((k>>5)*128 + col)*4 + ((k>>3)&3))*8 + (k&7)]
__global__ void k_packW(const float* __restrict__ W, ushort* __restrict__ Wh,
                        ushort* __restrict__ Wl) {
  int idx = blockIdx.x * 256 + threadIdx.x;
  if (idx >= FD * FD) return;
  int k = idx >> 7, col = idx & 127;
  float v = W[idx];
  ushort h = f2bf(v);
  ushort l = f2bf(v - bf2f(h));
  size_t o = ((((size_t)(k >> 5)) * 128 + col) * 4 + ((k >> 3) & 3)) * 8 + (k & 7);
  Wh[o] = h; Wl[o] = l;
}

// ---------- MFMA GEMM: Qh = bf16( dinv[row] * ((Ah+Al)@(Wh+Wl)) ) ----------
__global__ __launch_bounds__(256, 4) void k_gemm_mfma(
    const ushort* __restrict__ Ah, const ushort* __restrict__ Al,
    const ushort* __restrict__ Bh, const ushort* __restrict__ Bl,
    const float* __restrict__ dinv, ushort* __restrict__ Qh) {
  int tid = threadIdx.x;
  int wave = tid >> 6, lane = tid & 63;
  int m15 = lane & 15, k0 = lane >> 4;
  int row0 = blockIdx.x * 64 + wave * 16;

  int ar = row0 + m15; if (ar >= NN) ar = NN - 1;
  short8v ah[4], al[4];
#pragma unroll
  for (int kc = 0; kc < 4; ++kc) {
    const ushort* p = Ah + (size_t)ar * FD + kc * 32 + k0 * 8;
    const ushort* q = Al + (size_t)ar * FD + kc * 32 + k0 * 8;
    ah[kc] = *(const short8v*)p;
    al[kc] = *(const short8v*)q;
  }

  int orow = row0 + k0 * 4;
  float dv[4];
#pragma unroll
  for (int j = 0; j < 4; ++j) {
    int r = orow + j;
    dv[j] = (r < NN) ? dinv[r] : 0.f;
  }

#pragma unroll
  for (int nt = 0; nt < 8; ++nt) {
    int col = nt * 16 + m15;
    f32x4 acc = {0.f, 0.f, 0.f, 0.f};
#pragma unroll
    for (int kc = 0; kc < 4; ++kc) {
      size_t off = (((size_t)kc * 128 + col) * 4 + k0) * 8;
      short8v bh = *(const short8v*)(Bh + off);
      short8v bl = *(const short8v*)(Bl + off);
      acc = __builtin_amdgcn_mfma_f32_16x16x32_bf16(ah[kc], bh, acc, 0, 0, 0);
      acc = __builtin_amdgcn_mfma_f32_16x16x32_bf16(ah[kc], bl, acc, 0, 0, 0);
      acc = __builtin_amdgcn_mfma_f32_16x16x32_bf16(al[kc], bh, acc, 0, 0, 0);
    }
#pragma unroll
    for (int j = 0; j < 4; ++j) {
      int r = orow + j;
      if (r < NN) Qh[(size_t)r * FD + col] = f2bf(dv[j] * acc[j]);
    }
  }
}

// ---------- gather: Ph,Pl = split( relu( dinv[i]*sum_e Qh[src_e] + b ) ) ----------
__global__ void k_gather(const int* __restrict__ rowptr, const int* __restrict__ csr_src,
                         const ushort* __restrict__ Qh, const float* __restrict__ b,
                         const float* __restrict__ dinv,
                         ushort* __restrict__ Ph, ushort* __restrict__ Pl) {
  int node = blockIdx.x * 8 + (threadIdx.x >> 5);
  if (node >= NN) return;
  int lane = threadIdx.x & 31;
  const ushort4* __restrict__ Q4 = (const ushort4*)Qh;
  float4 acc = {0.f, 0.f, 0.f, 0.f};
  int e0 = rowptr[node], e1 = rowptr[node + 1];
  int e = e0;
  for (; e + 3 < e1; e += 4) {
    int s0 = csr_src[e], s1 = csr_src[e + 1], s2 = csr_src[e + 2], s3 = csr_src[e + 3];
    ushort4 q0 = Q4[(size_t)s0 * 32 + lane];
    ushort4 q1 = Q4[(size_t)s1 * 32 + lane];
    ushort4 q2 = Q4[(size_t)s2 * 32 + lane];
    ushort4 q3 = Q4[(size_t)s3 * 32 + lane];
    acc.x += (bf2f(q0.x) + bf2f(q1.x)) + (bf2f(q2.x) + bf2f(q3.x));
    acc.y += (bf2f(q0.y) + bf2f(q1.y)) + (bf2f(q2.y) + bf2f(q3.y));
    acc.z += (bf2f(q0.z) + bf2f(q1.z)) + (bf2f(q2.z) + bf2f(q3.z));
    acc.w += (bf2f(q0.w) + bf2f(q1.w)) + (bf2f(q2.w) + bf2f(q3.w));
  }
  for (; e < e1; ++e) {
    int s0 = csr_src[e];
    ushort4 q0 = Q4[(size_t)s0 * 32 + lane];
    acc.x += bf2f(q0.x); acc.y += bf2f(q0.y);
    acc.z += bf2f(q0.z); acc.w += bf2f(q0.w);
  }
  float di = dinv[node];
  float4 bv = ((const float4*)b)[lane];
  acc.x = fmaxf(fmaf(di, acc.x, bv.x), 0.f);
  acc.y = fmaxf(fmaf(di, acc.y, bv.y), 0.f);
  acc.z = fmaxf(fmaf(di, acc.z, bv.z), 0.f);
  acc.w = fmaxf(fmaf(di, acc.w, bv.w), 0.f);
  ushort4 h, l;
  h.x = f2bf(acc.x); l.x = f2bf(acc.x - bf2f(h.x));
  h.y = f2bf(acc.y); l.y = f2bf(acc.y - bf2f(h.y));
  h.z = f2bf(acc.z); l.z = f2bf(acc.z - bf2f(h.z));
  h.w = f2bf(acc.w); l.w = f2bf(acc.w - bf2f(h.w));
  size_t o = (size_t)node * 32 + lane;
  ((ushort4*)Ph)[o] = h;
  ((ushort4*)Pl)[o] = l;
}

// ---------- pooling + head ----------

__global__ void k_zero_pool(float* __restrict__ sums, float* __restrict__ counts) {
  int t = blockIdx.x * 256 + threadIdx.x;
  if (t < NG * FD) sums[t] = 0.f;
  if (t < NG) counts[t] = 0.f;
}

#define POOL_BLOCKS 1024
#define POOL_CHUNK 98
__global__ void k_pool(const int* __restrict__ batch, const ushort* __restrict__ Ph,
                       const ushort* __restrict__ Pl, float* __restrict__ sums,
                       float* __restrict__ counts) {
  int f = threadIdx.x;  // 0..127
  int i0 = blockIdx.x * POOL_CHUNK;
  if (i0 >= NN) return;
  int i1 = i0 + POOL_CHUNK;
  if (i1 > NN) i1 = NN;
  float acc = 0.f;
  int gcur = batch[i0];
  int cnt = 0;
  for (int i = i0; i < i1; ++i) {
    int g = batch[i];
    if (g != gcur) {
      atomicAdd(&sums[gcur * FD + f], acc);
      if (f == 0) atomicAdd(&counts[gcur], (float)cnt);
      acc = 0.f; cnt = 0; gcur = g;
    }
    size_t o = (size_t)i * FD + f;
    acc += bf2f(Ph[o]) + bf2f(Pl[o]);
    ++cnt;
  }
  atomicAdd(&sums[gcur * FD + f], acc);
  if (f == 0) atomicAdd(&counts[gcur], (float)cnt);
}

__global__ void k_head(const float* __restrict__ sums, const float* __restrict__ counts,
                       const float* __restrict__ Wm, const float* __restrict__ bm,
                       float* __restrict__ out) {
  int t = blockIdx.x * 256 + threadIdx.x;
  if (t >= NG * NC) return;
  int g = t / NC, c = t % NC;
  float inv = 1.0f / fmaxf(counts[g], 1.0f);
  float s = 0.f;
#pragma unroll 4
  for (int f = 0; f < FD; ++f) s = fmaf(sums[g * FD + f] * inv, Wm[f * NC + c], s);
  out[t] = s + bm[c];
}

extern "C" void kernel_launch(void* const* d_in, const int* in_sizes, int n_in,
                              void* d_out, int out_size, void* d_ws, size_t ws_size,
                              hipStream_t stream) {
  const float* x     = (const float*)d_in[0];
  const int*   ei    = (const int*)d_in[1];
  const int*   batch = (const int*)d_in[2];
  const float* W_in  = (const float*)d_in[3];
  const float* b_in  = (const float*)d_in[4];
  const float* W_mid = (const float*)d_in[5];
  const float* b_mid = (const float*)d_in[6];
  const float* W_mlp = (const float*)d_in[7];
  const float* b_mlp = (const float*)d_in[8];
  float* out = (float*)d_out;

  const int* src = ei;        // edge_index[0]
  const int* dst = ei + NE;   // edge_index[1]

  char* ws = (char*)d_ws;
  ushort*   Qh      = (ushort*)ws;    ws += (size_t)NN * FD * 2;   // 25.6 MB
  ushort*   Ph      = (ushort*)ws;    ws += (size_t)NN * FD * 2;   // 25.6 MB
  ushort*   Pl      = (ushort*)ws;    ws += (size_t)NN * FD * 2;   // 25.6 MB
  float*    dinv    = (float*)ws;     ws += (size_t)NN * 4;
  int*      rowptr  = (int*)ws;       ws += (size_t)(NN + 1) * 4;
  int*      csr_src = (int*)ws;       ws += (size_t)NT * 4;        // 6.8 MB
  unsigned* binned  = (unsigned*)ws;  ws += (size_t)NE * 4;        // 6.4 MB
  int*      bcnt    = (int*)ws;       ws += (size_t)NBKT * 4;
  int*      boff    = (int*)ws;       ws += (size_t)(NBKT + 1) * 4;
  int*      bcur    = (int*)ws;       ws += (size_t)NBKT * 4;
  ushort*   WhA     = (ushort*)ws;    ws += (size_t)FD * FD * 2;
  ushort*   WlA     = (ushort*)ws;    ws += (size_t)FD * FD * 2;
  ushort*   WhB     = (ushort*)ws;    ws += (size_t)FD * FD * 2;
  ushort*   WlB     = (ushort*)ws;    ws += (size_t)FD * FD * 2;
  float*    sums    = (float*)ws;     ws += (size_t)NG * FD * 4;
  float*    counts  = (float*)ws;     ws += (size_t)NG * 4;

  // binned CSR build (incl. self-loops; reused by all 4 layers)
  k_zero_int<<<(NBKT + 255) / 256, 256, 0, stream>>>(bcnt, NBKT);
  k_bcount<<<(NE + 255) / 256, 256, 0, stream>>>(dst, bcnt);
  k_bscan<<<1, 1024, 0, stream>>>(bcnt, boff, bcur);
  k_bfill<<<(NE + 255) / 256, 256, 0, stream>>>(src, dst, boff, bcur, binned);
  k_csr_bucket<<<NBKT, 256, 0, stream>>>(boff, binned, rowptr, dinv, csr_src);

  // weight packing + input split
  k_packW<<<(FD * FD + 255) / 256, 256, 0, stream>>>(W_in, WhA, WlA);
  k_packW<<<(FD * FD + 255) / 256, 256, 0, stream>>>(W_mid, WhB, WlB);
  k_split<<<(NN * FD / 4 + 255) / 256, 256, 0, stream>>>(x, Ph, Pl);

  const int gM = (NN + 63) / 64;   // 1563 blocks
  const int gG = (NN + 7) / 8;     // 12500 blocks
  for (int L = 0; L < 4; ++L) {
    const ushort* Wh = (L == 0) ? WhA : WhB;
    const ushort* Wl = (L == 0) ? WlA : WlB;
    const float*  b  = (L == 0) ? b_in : b_mid;
    k_gemm_mfma<<<gM, 256, 0, stream>>>(Ph, Pl, Wh, Wl, dinv, Qh);
    k_gather<<<gG, 256, 0, stream>>>(rowptr, csr_src, Qh, b, dinv, Ph, Pl);
  }

  k_zero_pool<<<32, 256, 0, stream>>>(sums, counts);
  k_pool<<<POOL_BLOCKS, 128, 0, stream>>>(batch, Ph, Pl, sums, counts);
  k_head<<<(NG * NC + 255) / 256, 256, 0, stream>>>(sums, counts, W_mlp, b_mlp, out);
}

// Round 10
// 620.063 us; speedup vs baseline: 2.0200x; 2.0200x over previous
//
#include <hip/hip_runtime.h>

#define NN 100000
#define NE 1600000
#define NT (NE + NN)     // edges incl. self-loops
#define FD 128
#define NC 10
#define NG 64

#define NBKT ((NN + 127) >> 7)   // 782 buckets of 128 nodes
#define NBC (NBKT * 64)          // 50048 replicated cursors (64 per bucket)
#define SCB 98                   // scan blocks: 98*512 = 50176 >= NBC
#define CAP 3072                 // LDS edge cap per bucket (mean 2046, sigma ~45)

typedef __attribute__((ext_vector_type(8))) short short8v;   // 8 bf16 (4 VGPRs)
typedef __attribute__((ext_vector_type(4))) float f32x4;

__device__ inline ushort f2bf(float x) {                     // round-to-nearest-even
  unsigned u = __float_as_uint(x);
  return (ushort)((u + 0x7FFF + ((u >> 16) & 1)) >> 16);
}
__device__ inline float bf2f(ushort h) { return __uint_as_float(((unsigned)h) << 16); }

// ---------- binned CSR build (64 cursor replicas per bucket) ----------

__global__ void k_zero_int(int* __restrict__ a, int n) {
  int i = blockIdx.x * 256 + threadIdx.x;
  if (i < n) a[i] = 0;
}

__global__ void k_bcount(const int* __restrict__ dst, int* __restrict__ bcnt) {
  int e = blockIdx.x * 256 + threadIdx.x;
  if (e < NE) {
    int d = dst[e];
    atomicAdd(&bcnt[((d >> 7) << 6) | (threadIdx.x & 63)], 1);
  }
}

// generic 3-phase exclusive scan over NBC counters -> boff; zeroes bcur
__global__ void k_gscanA(const int* __restrict__ cnt, int* __restrict__ blockSums) {
  __shared__ int red[256];
  int t = threadIdx.x, b = blockIdx.x;
  int i0 = b * 512 + t * 2;
  int s = 0;
#pragma unroll
  for (int j = 0; j < 2; ++j) { int i = i0 + j; if (i < NBC) s += cnt[i]; }
  red[t] = s;
  __syncthreads();
  for (int off = 128; off > 0; off >>= 1) {
    if (t < off) red[t] += red[t + off];
    __syncthreads();
  }
  if (t == 0) blockSums[b] = red[0];
}

__global__ void k_gscanB(const int* __restrict__ blockSums, int* __restrict__ blockOffs,
                         int* __restrict__ boff) {
  __shared__ int sh[128];
  int t = threadIdx.x;
  int v = (t < SCB) ? blockSums[t] : 0;
  sh[t] = v;
  __syncthreads();
  for (int off = 1; off < 128; off <<= 1) {
    int u = (t >= off) ? sh[t - off] : 0;
    __syncthreads();
    sh[t] += u;
    __syncthreads();
  }
  if (t < SCB) blockOffs[t] = sh[t] - v;   // exclusive
  if (t == 127) boff[NBC] = sh[127];       // total = NE
}

__global__ void k_gscanC(const int* __restrict__ cnt, const int* __restrict__ blockOffs,
                         int* __restrict__ boff, int* __restrict__ bcur) {
  __shared__ int sh[256];
  int t = threadIdx.x, b = blockIdx.x;
  int i0 = b * 512 + t * 2;
  int c[2];
  int s = 0;
#pragma unroll
  for (int j = 0; j < 2; ++j) {
    int i = i0 + j;
    c[j] = (i < NBC) ? cnt[i] : 0;
    s += c[j];
  }
  sh[t] = s;
  __syncthreads();
  for (int off = 1; off < 256; off <<= 1) {
    int u = (t >= off) ? sh[t - off] : 0;
    __syncthreads();
    sh[t] += u;
    __syncthreads();
  }
  int run = blockOffs[b] + sh[t] - s;
#pragma unroll
  for (int j = 0; j < 2; ++j) {
    int i = i0 + j;
    if (i < NBC) {
      boff[i] = run;
      bcur[i] = 0;
      run += c[j];
    }
  }
}

// append packed (local_dst<<17 | src) via the lane's replica cursor
__global__ void k_bfill(const int* __restrict__ src, const int* __restrict__ dst,
                        const int* __restrict__ boff, int* __restrict__ bcur,
                        unsigned* __restrict__ binned) {
  int e = blockIdx.x * 256 + threadIdx.x;
  if (e >= NE) return;
  int d = dst[e], s = src[e];
  int c = ((d >> 7) << 6) | (threadIdx.x & 63);
  int slot = boff[c] + atomicAdd(&bcur[c], 1);
  binned[slot] = ((unsigned)(d & 127) << 17) | (unsigned)s;
}

// one block per bucket: local degree count, local scan (+self), emit rowptr/dinv,
// LDS scatter, contiguous coalesced CSR write. Fallback to global scatter if >CAP.
__global__ __launch_bounds__(256) void k_csr_bucket(
    const int* __restrict__ boff, const unsigned* __restrict__ binned,
    int* __restrict__ rowptr, float* __restrict__ dinv, int* __restrict__ csr_src) {
  __shared__ unsigned varr[CAP];
  __shared__ int earr[CAP + 128];
  __shared__ int deg[128];
  __shared__ int sh[128];
  int b = blockIdx.x, tid = threadIdx.x;
  int e0 = boff[b << 6], e1 = boff[(b + 1) << 6], seg = e1 - e0;
  int n0 = b << 7;
  int nb = NN - n0; if (nb > 128) nb = 128;
  int gbase = e0 + n0;                      // + one self per preceding node
  if (tid < 128) deg[tid] = 0;
  __syncthreads();
  bool fast = (seg <= CAP);
  if (fast) {
    for (int i = tid; i < seg; i += 256) {
      unsigned v = binned[e0 + i];
      varr[i] = v;
      atomicAdd(&deg[(v >> 17) & 127], 1);
    }
  } else {
    for (int i = tid; i < seg; i += 256) {
      unsigned v = binned[e0 + i];
      atomicAdd(&deg[(v >> 17) & 127], 1);
    }
  }
  __syncthreads();
  int dl = 0;
  if (tid < 128) {
    dl = (tid < nb) ? deg[tid] + 1 : 0;     // +1 self-loop
    sh[tid] = dl;
  }
  __syncthreads();
  for (int off = 1; off < 128; off <<= 1) {
    int u = 0;
    if (tid < 128 && tid >= off) u = sh[tid - off];
    __syncthreads();
    if (tid < 128) sh[tid] += u;
    __syncthreads();
  }
  int excl = 0;
  if (tid < nb) {
    excl = sh[tid] - dl;
    rowptr[n0 + tid] = gbase + excl;
    dinv[n0 + tid] = rsqrtf((float)dl);
    if (fast) earr[excl] = n0 + tid;        // self-loop in first slot
    else      csr_src[gbase + excl] = n0 + tid;
  }
  __syncthreads();
  if (tid < 128) deg[tid] = (tid < nb) ? (excl + 1) : 0;   // cursor after self
  __syncthreads();
  if (fast) {
    for (int i = tid; i < seg; i += 256) {
      unsigned v = varr[i];
      int l = (v >> 17) & 127;
      int pos = atomicAdd(&deg[l], 1);
      earr[pos] = (int)(v & 0x1FFFF);
    }
    __syncthreads();
    int tot = seg + nb;
    for (int i = tid; i < tot; i += 256) csr_src[gbase + i] = earr[i];
  } else {
    for (int i = tid; i < seg; i += 256) {
      unsigned v = binned[e0 + i];
      int l = (v >> 17) & 127;
      int pos = atomicAdd(&deg[l], 1);
      csr_src[gbase + pos] = (int)(v & 0x1FFFF);
    }
  }
  if (b == 0 && tid == 0) rowptr[NN] = NT;
}

// ---------- split-bf16 prep ----------

__global__ void k_split(const float* __restrict__ X, ushort* __restrict__ Hh,
                        ushort* __restrict__ Hl) {
  int t = blockIdx.x * 256 + threadIdx.x;
  if (t >= NN * FD / 4) return;
  float4 v = ((const float4*)X)[t];
  ushort4 h, l;
  h.x = f2bf(v.x); l.x = f2bf(v.x - bf2f(h.x));
  h.y = f2bf(v.y); l.y = f2bf(v.y - bf2f(h.y));
  h.z = f2bf(v.z); l.z = f2bf(v.z - bf2f(h.z));
  h.w = f2bf(v.w); l.w = f2bf(v.w - bf2f(h.w));
  ((ushort4*)Hh)[t] = h;
  ((ushort4*)Hl)[t] = l;
}

// Pack W[k][col] into MFMA B-fragment order, split hi/lo:
// packed[(((k>>5)*128 + col)*4 + ((k>>3)&3))*8 + (k&7)]
__global__ void k_packW(const float* __restrict__ W, ushort* __restrict__ Wh,
                        ushort* __restrict__ Wl) {
  int idx = blockIdx.x * 256 + threadIdx.x;
  if (idx >= FD * FD) return;
  int k = idx >> 7, col = idx & 127;
  float v = W[idx];
  ushort h = f2bf(v);
  ushort l = f2bf(v - bf2f(h));
  size_t o = ((((size_t)(k >> 5)) * 128 + col) * 4 + ((k >> 3) & 3)) * 8 + (k & 7);
  Wh[o] = h; Wl[o] = l;
}

// ---------- MFMA GEMM: Qh = bf16( dinv[row] * ((Ah+Al)@(Wh+Wl)) ) ----------
// 32 rows/wave (two 16-row A-frag sets): halves B traffic, doubles MFMA ILP.
__global__ __launch_bounds__(256, 3) void k_gemm_mfma(
    const ushort* __restrict__ Ah, const ushort* __restrict__ Al,
    const ushort* __restrict__ Bh, const ushort* __restrict__ Bl,
    const float* __restrict__ dinv, ushort* __restrict__ Qh) {
  int tid = threadIdx.x;
  int wave = tid >> 6, lane = tid & 63;
  int m15 = lane & 15, k0 = lane >> 4;
  int row0 = blockIdx.x * 128 + wave * 32;

  int ar0 = row0 + m15;      if (ar0 >= NN) ar0 = NN - 1;
  int ar1 = row0 + 16 + m15; if (ar1 >= NN) ar1 = NN - 1;
  short8v ah0[4], al0[4], ah1[4], al1[4];
#pragma unroll
  for (int kc = 0; kc < 4; ++kc) {
    size_t o0 = (size_t)ar0 * FD + kc * 32 + k0 * 8;
    size_t o1 = (size_t)ar1 * FD + kc * 32 + k0 * 8;
    ah0[kc] = *(const short8v*)(Ah + o0);
    al0[kc] = *(const short8v*)(Al + o0);
    ah1[kc] = *(const short8v*)(Ah + o1);
    al1[kc] = *(const short8v*)(Al + o1);
  }

  int orow0 = row0 + k0 * 4;
  int orow1 = row0 + 16 + k0 * 4;
  float dv0[4], dv1[4];
#pragma unroll
  for (int j = 0; j < 4; ++j) {
    int r0 = orow0 + j; dv0[j] = (r0 < NN) ? dinv[r0] : 0.f;
    int r1 = orow1 + j; dv1[j] = (r1 < NN) ? dinv[r1] : 0.f;
  }

#pragma unroll
  for (int nt = 0; nt < 8; ++nt) {
    int col = nt * 16 + m15;
    f32x4 acc0 = {0.f, 0.f, 0.f, 0.f};
    f32x4 acc1 = {0.f, 0.f, 0.f, 0.f};
#pragma unroll
    for (int kc = 0; kc < 4; ++kc) {
      size_t off = (((size_t)kc * 128 + col) * 4 + k0) * 8;
      short8v bh = *(const short8v*)(Bh + off);
      short8v bl = *(const short8v*)(Bl + off);
      acc0 = __builtin_amdgcn_mfma_f32_16x16x32_bf16(ah0[kc], bh, acc0, 0, 0, 0);
      acc1 = __builtin_amdgcn_mfma_f32_16x16x32_bf16(ah1[kc], bh, acc1, 0, 0, 0);
      acc0 = __builtin_amdgcn_mfma_f32_16x16x32_bf16(ah0[kc], bl, acc0, 0, 0, 0);
      acc1 = __builtin_amdgcn_mfma_f32_16x16x32_bf16(ah1[kc], bl, acc1, 0, 0, 0);
      acc0 = __builtin_amdgcn_mfma_f32_16x16x32_bf16(al0[kc], bh, acc0, 0, 0, 0);
      acc1 = __builtin_amdgcn_mfma_f32_16x16x32_bf16(al1[kc], bh, acc1, 0, 0, 0);
    }
#pragma unroll
    for (int j = 0; j < 4; ++j) {
      int r0 = orow0 + j;
      if (r0 < NN) Qh[(size_t)r0 * FD + col] = f2bf(dv0[j] * acc0[j]);
      int r1 = orow1 + j;
      if (r1 < NN) Qh[(size_t)r1 * FD + col] = f2bf(dv1[j] * acc1[j]);
    }
  }
}

// ---------- gather: Ph,Pl = split( relu( dinv[i]*sum_e Qh[src_e] + b ) ) ----------
__global__ void k_gather(const int* __restrict__ rowptr, const int* __restrict__ csr_src,
                         const ushort* __restrict__ Qh, const float* __restrict__ b,
                         const float* __restrict__ dinv,
                         ushort* __restrict__ Ph, ushort* __restrict__ Pl) {
  int node = blockIdx.x * 8 + (threadIdx.x >> 5);
  if (node >= NN) return;
  int lane = threadIdx.x & 31;
  const ushort4* __restrict__ Q4 = (const ushort4*)Qh;
  float4 acc = {0.f, 0.f, 0.f, 0.f};
  int e0 = rowptr[node], e1 = rowptr[node + 1];
  int e = e0;
  for (; e + 3 < e1; e += 4) {
    int s0 = csr_src[e], s1 = csr_src[e + 1], s2 = csr_src[e + 2], s3 = csr_src[e + 3];
    ushort4 q0 = Q4[(size_t)s0 * 32 + lane];
    ushort4 q1 = Q4[(size_t)s1 * 32 + lane];
    ushort4 q2 = Q4[(size_t)s2 * 32 + lane];
    ushort4 q3 = Q4[(size_t)s3 * 32 + lane];
    acc.x += (bf2f(q0.x) + bf2f(q1.x)) + (bf2f(q2.x) + bf2f(q3.x));
    acc.y += (bf2f(q0.y) + bf2f(q1.y)) + (bf2f(q2.y) + bf2f(q3.y));
    acc.z += (bf2f(q0.z) + bf2f(q1.z)) + (bf2f(q2.z) + bf2f(q3.z));
    acc.w += (bf2f(q0.w) + bf2f(q1.w)) + (bf2f(q2.w) + bf2f(q3.w));
  }
  for (; e < e1; ++e) {
    int s0 = csr_src[e];
    ushort4 q0 = Q4[(size_t)s0 * 32 + lane];
    acc.x += bf2f(q0.x); acc.y += bf2f(q0.y);
    acc.z += bf2f(q0.z); acc.w += bf2f(q0.w);
  }
  float di = dinv[node];
  float4 bv = ((const float4*)b)[lane];
  acc.x = fmaxf(fmaf(di, acc.x, bv.x), 0.f);
  acc.y = fmaxf(fmaf(di, acc.y, bv.y), 0.f);
  acc.z = fmaxf(fmaf(di, acc.z, bv.z), 0.f);
  acc.w = fmaxf(fmaf(di, acc.w, bv.w), 0.f);
  ushort4 h, l;
  h.x = f2bf(acc.x); l.x = f2bf(acc.x - bf2f(h.x));
  h.y = f2bf(acc.y); l.y = f2bf(acc.y - bf2f(h.y));
  h.z = f2bf(acc.z); l.z = f2bf(acc.z - bf2f(h.z));
  h.w = f2bf(acc.w); l.w = f2bf(acc.w - bf2f(h.w));
  size_t o = (size_t)node * 32 + lane;
  ((ushort4*)Ph)[o] = h;
  ((ushort4*)Pl)[o] = l;
}

// ---------- pooling + head ----------

__global__ void k_zero_pool(float* __restrict__ sums, float* __restrict__ counts) {
  int t = blockIdx.x * 256 + threadIdx.x;
  if (t < NG * FD) sums[t] = 0.f;
  if (t < NG) counts[t] = 0.f;
}

#define POOL_BLOCKS 1024
#define POOL_CHUNK 98
__global__ void k_pool(const int* __restrict__ batch, const ushort* __restrict__ Ph,
                       const ushort* __restrict__ Pl, float* __restrict__ sums,
                       float* __restrict__ counts) {
  int f = threadIdx.x;  // 0..127
  int i0 = blockIdx.x * POOL_CHUNK;
  if (i0 >= NN) return;
  int i1 = i0 + POOL_CHUNK;
  if (i1 > NN) i1 = NN;
  float acc = 0.f;
  int gcur = batch[i0];
  int cnt = 0;
  for (int i = i0; i < i1; ++i) {
    int g = batch[i];
    if (g != gcur) {
      atomicAdd(&sums[gcur * FD + f], acc);
      if (f == 0) atomicAdd(&counts[gcur], (float)cnt);
      acc = 0.f; cnt = 0; gcur = g;
    }
    size_t o = (size_t)i * FD + f;
    acc += bf2f(Ph[o]) + bf2f(Pl[o]);
    ++cnt;
  }
  atomicAdd(&sums[gcur * FD + f], acc);
  if (f == 0) atomicAdd(&counts[gcur], (float)cnt);
}

__global__ void k_head(const float* __restrict__ sums, const float* __restrict__ counts,
                       const float* __restrict__ Wm, const float* __restrict__ bm,
                       float* __restrict__ out) {
  int t = blockIdx.x * 256 + threadIdx.x;
  if (t >= NG * NC) return;
  int g = t / NC, c = t % NC;
  float inv = 1.0f / fmaxf(counts[g], 1.0f);
  float s = 0.f;
#pragma unroll 4
  for (int f = 0; f < FD; ++f) s = fmaf(sums[g * FD + f] * inv, Wm[f * NC + c], s);
  out[t] = s + bm[c];
}

extern "C" void kernel_launch(void* const* d_in, const int* in_sizes, int n_in,
                              void* d_out, int out_size, void* d_ws, size_t ws_size,
                              hipStream_t stream) {
  const float* x     = (const float*)d_in[0];
  const int*   ei    = (const int*)d_in[1];
  const int*   batch = (const int*)d_in[2];
  const float* W_in  = (const float*)d_in[3];
  const float* b_in  = (const float*)d_in[4];
  const float* W_mid = (const float*)d_in[5];
  const float* b_mid = (const float*)d_in[6];
  const float* W_mlp = (const float*)d_in[7];
  const float* b_mlp = (const float*)d_in[8];
  float* out = (float*)d_out;

  const int* src = ei;        // edge_index[0]
  const int* dst = ei + NE;   // edge_index[1]

  char* ws = (char*)d_ws;
  ushort*   Qh      = (ushort*)ws;    ws += (size_t)NN * FD * 2;   // 25.6 MB
  ushort*   Ph      = (ushort*)ws;    ws += (size_t)NN * FD * 2;   // 25.6 MB
  ushort*   Pl      = (ushort*)ws;    ws += (size_t)NN * FD * 2;   // 25.6 MB
  float*    dinv    = (float*)ws;     ws += (size_t)NN * 4;
  int*      rowptr  = (int*)ws;       ws += (size_t)(NN + 1) * 4;
  int*      csr_src = (int*)ws;       ws += (size_t)NT * 4;        // 6.8 MB
  unsigned* binned  = (unsigned*)ws;  ws += (size_t)NE * 4;        // 6.4 MB
  int*      bcnt    = (int*)ws;       ws += (size_t)NBC * 4;       // 200 KB
  int*      boff    = (int*)ws;       ws += (size_t)(NBC + 1) * 4;
  int*      bcur    = (int*)ws;       ws += (size_t)NBC * 4;
  int*      bSums   = (int*)ws;       ws += 128 * 4;
  int*      bOffs   = (int*)ws;       ws += 128 * 4;
  ushort*   WhA     = (ushort*)ws;    ws += (size_t)FD * FD * 2;
  ushort*   WlA     = (ushort*)ws;    ws += (size_t)FD * FD * 2;
  ushort*   WhB     = (ushort*)ws;    ws += (size_t)FD * FD * 2;
  ushort*   WlB     = (ushort*)ws;    ws += (size_t)FD * FD * 2;
  float*    sums    = (float*)ws;     ws += (size_t)NG * FD * 4;
  float*    counts  = (float*)ws;     ws += (size_t)NG * 4;

  // binned CSR build (incl. self-loops; reused by all 4 layers)
  k_zero_int<<<(NBC + 255) / 256, 256, 0, stream>>>(bcnt, NBC);
  k_bcount<<<(NE + 255) / 256, 256, 0, stream>>>(dst, bcnt);
  k_gscanA<<<SCB, 256, 0, stream>>>(bcnt, bSums);
  k_gscanB<<<1, 128, 0, stream>>>(bSums, bOffs, boff);
  k_gscanC<<<SCB, 256, 0, stream>>>(bcnt, bOffs, boff, bcur);
  k_bfill<<<(NE + 255) / 256, 256, 0, stream>>>(src, dst, boff, bcur, binned);
  k_csr_bucket<<<NBKT, 256, 0, stream>>>(boff, binned, rowptr, dinv, csr_src);

  // weight packing + input split
  k_packW<<<(FD * FD + 255) / 256, 256, 0, stream>>>(W_in, WhA, WlA);
  k_packW<<<(FD * FD + 255) / 256, 256, 0, stream>>>(W_mid, WhB, WlB);
  k_split<<<(NN * FD / 4 + 255) / 256, 256, 0, stream>>>(x, Ph, Pl);

  const int gM = (NN + 127) / 128;   // 782 blocks, 128 rows each
  const int gG = (NN + 7) / 8;       // 12500 blocks
  for (int L = 0; L < 4; ++L) {
    const ushort* Wh = (L == 0) ? WhA : WhB;
    const ushort* Wl = (L == 0) ? WlA : WlB;
    const float*  b  = (L == 0) ? b_in : b_mid;
    k_gemm_mfma<<<gM, 256, 0, stream>>>(Ph, Pl, Wh, Wl, dinv, Qh);
    k_gather<<<gG, 256, 0, stream>>>(rowptr, csr_src, Qh, b, dinv, Ph, Pl);
  }

  k_zero_pool<<<32, 256, 0, stream>>>(sums, counts);
  k_pool<<<POOL_BLOCKS, 128, 0, stream>>>(batch, Ph, Pl, sums, counts);
  k_head<<<(NG * NC + 255) / 256, 256, 0, stream>>>(sums, counts, W_mlp, b_mlp, out);
}